// Round 16
// baseline (158.965 us; speedup 1.0000x reference)
//
#include <hip/hip_runtime.h>

#define NN 100000
#define NE 1600000
#define NBK 392        // ceil(100000/256) buckets of 256 nodes
#define CAPB 6144      // per-bucket edge capacity (mean 4082)
#define CVTB 6250      // (NN*64)/1024 blocks for x->bf16
#define SLABU (NN * 32)  // ushorts per 32-feat slab

typedef __attribute__((ext_vector_type(8))) short bf16x8;
typedef __attribute__((ext_vector_type(4))) float f32x4;

__device__ __forceinline__ unsigned short f2b(float f) {
  unsigned b = __float_as_uint(f);
  unsigned r = b + 0x7FFF + ((b >> 16) & 1);  // RNE
  return (unsigned short)(r >> 16);
}

__global__ void k_zero(int* __restrict__ g) {
  if (threadIdx.x < NBK) g[threadIdx.x] = 0;
}

// Fused prologue: [0,CVTB) x->bf16 (2-slab layout) | CVTB: WT1 | CVTB+1: WT2 | rest: partA.
__global__ void k_pre(const float* __restrict__ x, unsigned short* __restrict__ xb,
                      const float* __restrict__ W1l, const float* __restrict__ W1r,
                      unsigned short* __restrict__ WT1,
                      const float* __restrict__ W2l, const float* __restrict__ W2r,
                      unsigned short* __restrict__ WT2,
                      const int* __restrict__ src, const int* __restrict__ dst,
                      int* __restrict__ gcur, unsigned* __restrict__ pairbuf) {
  __shared__ int hist[NBK];
  __shared__ int sc[512];
  __shared__ int base[NBK], lofs[NBK];
  __shared__ unsigned epk[4096];
  __shared__ unsigned short ebk[4096];
  int t = threadIdx.x;
  int b = blockIdx.x;
  if (b < CVTB) {
    int i = (b * 256 + t) * 4;
    int n = i >> 6, f = i & 63;
    float4 v = *(const float4*)(x + i);
    ushort4 o;
    o.x = f2b(v.x); o.y = f2b(v.y); o.z = f2b(v.z); o.w = f2b(v.w);
    // slab layout: feat f of node n -> xb[(f>>5)*SLABU + n*32 + (f&31)]
    *(ushort4*)(xb + (size_t)(f >> 5) * SLABU + (size_t)n * 32 + (f & 31)) = o;
    return;
  }
  if (b == CVTB) {
    for (int i = t; i < 64 * 128; i += 256) {
      int f = i >> 7, k = i & 127;
      WT1[i] = f2b((k < 64) ? W1l[k * 64 + f] : W1r[(k - 64) * 64 + f]);
    }
    return;
  }
  if (b == CVTB + 1) {
    for (int i = t; i < 32 * 128; i += 256) {
      int f = i >> 7, k = i & 127;
      WT2[i] = f2b((k < 64) ? W2l[k * 32 + f] : W2r[(k - 64) * 32 + f]);
    }
    return;
  }
  // ---- partA ----
  int pb = b - (CVTB + 2);
  for (int i = t; i < NBK; i += 256) { hist[i] = 0; lofs[i] = 0; }
  __syncthreads();
  unsigned pk[16]; int bk[16];
  int e0 = pb * 4096 + t;
#pragma unroll
  for (int j = 0; j < 16; ++j) {
    int e = e0 + j * 256;
    if (e < NE) {
      int d = dst[e], s = src[e];
      bk[j] = d >> 8;
      pk[j] = ((unsigned)s << 8) | (unsigned)(d & 255);
      atomicAdd(&hist[bk[j]], 1);
    } else bk[j] = -1;
  }
  __syncthreads();
  sc[t] = (t < NBK) ? hist[t] : 0;
  sc[t + 256] = (t + 256 < NBK) ? hist[t + 256] : 0;
  __syncthreads();
  for (int off = 1; off < 512; off <<= 1) {
    int v0 = (t >= off) ? sc[t - off] : 0;
    int v1 = sc[t + 256 - off];
    __syncthreads();
    sc[t] += v0;
    sc[t + 256] += v1;
    __syncthreads();
  }
  for (int i = t; i < NBK; i += 256) {
    int h = hist[i];
    base[i] = atomicAdd(&gcur[i], h);
    hist[i] = sc[i] - h;
  }
  __syncthreads();
#pragma unroll
  for (int j = 0; j < 16; ++j) {
    if (bk[j] >= 0) {
      int pos = hist[bk[j]] + atomicAdd(&lofs[bk[j]], 1);
      epk[pos] = pk[j];
      ebk[pos] = (unsigned short)bk[j];
    }
  }
  __syncthreads();
  int cb = sc[511];
  for (int i = t; i < cb; i += 256) {
    unsigned p = epk[i];
    int bb = ebk[i];
    int slot = base[bb] + (i - hist[bb]);
    if (slot < CAPB) pairbuf[(size_t)bb * CAPB + slot] = p;
  }
}

// Pass B: one block (512 thr) per bucket. Count -> prefix -> LDS scatter -> writeout.
__global__ void k_partB(const unsigned* __restrict__ pairbuf, const int* __restrict__ gcur,
                        int* __restrict__ esrc, uint2* __restrict__ rowp2) {
  __shared__ int cnt[256], cur[256], ssum[256];
  __shared__ int ebuf[CAPB];
  int b = blockIdx.x, t = threadIdx.x;
  int cb = gcur[b]; if (cb > CAPB) cb = CAPB;
  if (t < 256) cnt[t] = 0;
  __syncthreads();
  const unsigned* pb = pairbuf + (size_t)b * CAPB;
  for (int i = t; i < cb; i += 512) atomicAdd(&cnt[pb[i] & 255], 1);
  __syncthreads();
  int a0 = (t < 256) ? cnt[t] : 0;
  if (t < 256) ssum[t] = a0;
  __syncthreads();
  for (int off = 1; off < 256; off <<= 1) {
    int tmp = (t < 256 && t >= off) ? ssum[t - off] : 0;
    __syncthreads();
    if (t < 256) ssum[t] += tmp;
    __syncthreads();
  }
  if (t < 256) {
    int ex = ssum[t] - a0;
    cur[t] = ex;
    int n = b * 256 + t;
    if (n < NN) rowp2[n] = make_uint2((unsigned)(b * CAPB + ex),
                                      (unsigned)(b * CAPB + ex + a0));
  }
  __syncthreads();
  for (int i = t; i < cb; i += 512) {
    unsigned p = pb[i];
    int pos = atomicAdd(&cur[p & 255], 1);
    ebuf[pos] = (int)(p >> 8);
  }
  __syncthreads();
  for (int i = t; i < cb; i += 512) esrc[(size_t)b * CAPB + i] = ebuf[i];
}

// Half-slab gather: one node per 8-LANE group; per edge the group reads one full
// 64B row (8 x uint2) of a 6.4MB slab (better L2 residency than 12.8MB).
// Same gather-instr count and in-flight ILP as the full-width version.
// shfl sources stay within the caller's own group -> ds_bpermute exec rule safe.
__global__ __launch_bounds__(256, 4) void k_agg(
    const uint2* __restrict__ slab_fb, const uint2* __restrict__ rowp2,
    const int* __restrict__ esrc, uint2* __restrict__ slab_out) {
  int tid = blockIdx.x * 256 + threadIdx.x;
  int node = tid >> 3;      // 32 nodes per block
  int c8 = tid & 7;
  int gbase = threadIdx.x & 56;
  unsigned long long rp =
      __builtin_nontemporal_load((const unsigned long long*)&rowp2[node]);
  int beg = (int)(unsigned)rp;
  int deg = (int)(unsigned)(rp >> 32) - beg;
  float a0 = 0.f, a1 = 0.f, a2 = 0.f, a3 = 0.f;

  int nfull = deg & ~7;
  for (int r0 = 0; r0 < nfull; r0 += 8) {
    int idxv = __builtin_nontemporal_load(&esrc[beg + r0 + c8]);
    int sv[8];
#pragma unroll
    for (int j = 0; j < 8; ++j) sv[j] = __shfl(idxv, gbase + j);
    uint2 v[8];
#pragma unroll
    for (int j = 0; j < 8; ++j) v[j] = slab_fb[(size_t)sv[j] * 8 + c8];
    __builtin_amdgcn_sched_barrier(0);  // keep gather batch above the accum chain
#pragma unroll
    for (int j = 0; j < 8; ++j) {
      a0 += __uint_as_float(v[j].x << 16);
      a1 += __uint_as_float(v[j].x & 0xFFFF0000u);
      a2 += __uint_as_float(v[j].y << 16);
      a3 += __uint_as_float(v[j].y & 0xFFFF0000u);
    }
  }
  int rem = deg - nfull;
  if (rem) {
    int idxv = __builtin_nontemporal_load(&esrc[beg + nfull + (c8 < rem ? c8 : 0)]);
    int sv[8];
#pragma unroll
    for (int j = 0; j < 8; ++j) sv[j] = __shfl(idxv, gbase + j);
    uint2 v[8];
#pragma unroll
    for (int j = 0; j < 8; ++j)
      if (j < rem) v[j] = slab_fb[(size_t)sv[j] * 8 + c8];
    __builtin_amdgcn_sched_barrier(0);
#pragma unroll
    for (int j = 0; j < 8; ++j)
      if (j < rem) {
        a0 += __uint_as_float(v[j].x << 16);
        a1 += __uint_as_float(v[j].x & 0xFFFF0000u);
        a2 += __uint_as_float(v[j].y << 16);
        a3 += __uint_as_float(v[j].y & 0xFFFF0000u);
      }
  }
  float inv = (deg > 0) ? (1.0f / (float)deg) : 0.f;
  unsigned lo = (unsigned)f2b(a0 * inv) | ((unsigned)f2b(a1 * inv) << 16);
  unsigned hi = (unsigned)f2b(a2 * inv) | ((unsigned)f2b(a3 * inv) << 16);
  unsigned long long ov = (unsigned long long)lo | ((unsigned long long)hi << 32);
  // nt store: aggb is read once by gemm; don't evict gather lines
  __builtin_nontemporal_store(ov,
      (unsigned long long*)(slab_out + (size_t)node * 8 + c8));
}

// MFMA GEMM: out[n][f] = sum_k [aggb|featb][n][k] * WT[f][k] + bias[f], K=128 bf16.
// aggb/featb are 2-slab layouts ([2][NN][32] ushort). ob (bf16 out) written in
// slab layout for the next layer's gather.
template <int NF>
__global__ __launch_bounds__(256) void k_gemm(
    const unsigned short* __restrict__ aggb, const unsigned short* __restrict__ featb,
    const unsigned short* __restrict__ WT, const float* __restrict__ bias,
    float* __restrict__ out, unsigned short* __restrict__ ob, int relu) {
  __shared__ unsigned short As[64 * 128];
  __shared__ unsigned short Ws[NF * 128];
  int tid = threadIdx.x;
  int n0 = blockIdx.x * 64;
  int lane = tid & 63, wr = tid >> 6;

  for (int cch = tid; cch < 64 * 16; cch += 256) {
    int r = cch >> 4, s = cch & 15;
    int n = n0 + r;
    bf16x8 v = {0, 0, 0, 0, 0, 0, 0, 0};
    if (n < NN) {
      int s8 = s & 7;
      const unsigned short* p = ((s < 8) ? aggb : featb) +
          (size_t)(s8 >> 2) * SLABU + (size_t)n * 32 + (s8 & 3) * 8;
      v = (s < 8) ? __builtin_nontemporal_load((const bf16x8*)p)
                  : *(const bf16x8*)p;
    }
    *(bf16x8*)(&As[r * 128 + ((s ^ (r & 15)) << 3)]) = v;
  }
  for (int cch = tid; cch < NF * 16; cch += 256) {
    int f = cch >> 4, s = cch & 15;
    bf16x8 v = *(const bf16x8*)(WT + f * 128 + s * 8);
    *(bf16x8*)(&Ws[f * 128 + ((s ^ (f & 15)) << 3)]) = v;
  }
  __syncthreads();

  int l15 = lane & 15, lg = lane >> 4;
  int arow = wr * 16 + l15;
  f32x4 acc[NF / 16];
#pragma unroll
  for (int ct = 0; ct < NF / 16; ++ct) acc[ct] = (f32x4){0.f, 0.f, 0.f, 0.f};

#pragma unroll
  for (int k0 = 0; k0 < 4; ++k0) {
    int sa = k0 * 4 + lg;
    bf16x8 a = *(const bf16x8*)(&As[arow * 128 + ((sa ^ (arow & 15)) << 3)]);
#pragma unroll
    for (int ct = 0; ct < NF / 16; ++ct) {
      int bcol = ct * 16 + l15;
      bf16x8 b = *(const bf16x8*)(&Ws[bcol * 128 + ((sa ^ (bcol & 15)) << 3)]);
      acc[ct] = __builtin_amdgcn_mfma_f32_16x16x32_bf16(a, b, acc[ct], 0, 0, 0);
    }
  }

#pragma unroll
  for (int ct = 0; ct < NF / 16; ++ct) {
    int f = ct * 16 + l15;
    float bv = bias[f];
#pragma unroll
    for (int r = 0; r < 4; ++r) {
      int n = n0 + wr * 16 + lg * 4 + r;
      if (n >= NN) continue;
      float v = acc[ct][r] + bv;
      if (relu) v = fmaxf(v, 0.f);
      if (out) out[(size_t)n * NF + f] = v;
      if (ob) ob[(size_t)(f >> 5) * SLABU + (size_t)n * 32 + (f & 31)] = f2b(v);
    }
  }
}

extern "C" void kernel_launch(void* const* d_in, const int* in_sizes, int n_in,
                              void* d_out, int out_size, void* d_ws, size_t ws_size,
                              hipStream_t stream) {
  const float* x   = (const float*)d_in[0];
  const int*   ei  = (const int*)d_in[1];
  const float* W1l = (const float*)d_in[2];
  const float* W1r = (const float*)d_in[3];
  const float* b1  = (const float*)d_in[4];
  const float* W2l = (const float*)d_in[5];
  const float* W2r = (const float*)d_in[6];
  const float* b2  = (const float*)d_in[7];
  const int* src = ei;
  const int* dst = ei + NE;
  float* out = (float*)d_out;

  char* ws = (char*)d_ws;
  size_t off = 0;
  auto take = [&](size_t bytes) -> char* {
    char* p = ws + off;
    off = (off + bytes + 255) & ~(size_t)255;
    return p;
  };
  int*      gcur    = (int*)take((size_t)NBK * 4);
  unsigned* pairbuf = (unsigned*)take((size_t)NBK * CAPB * 4);
  int*      esrc    = (int*)take((size_t)NBK * CAPB * 4);
  uint2*    rowp2   = (uint2*)take((size_t)NN * 8);
  unsigned short* aggb = (unsigned short*)take((size_t)NN * 64 * 2);
  unsigned short* xb   = (unsigned short*)take((size_t)NN * 64 * 2);
  unsigned short* hb   = (unsigned short*)take((size_t)NN * 64 * 2);
  unsigned short* WT1  = (unsigned short*)take((size_t)64 * 128 * 2);
  unsigned short* WT2  = (unsigned short*)take((size_t)32 * 128 * 2);

  int nbA = (NE + 4095) / 4096;  // 391
  k_zero<<<1, 512, 0, stream>>>(gcur);
  k_pre<<<CVTB + 2 + nbA, 256, 0, stream>>>(x, xb, W1l, W1r, WT1, W2l, W2r, WT2,
                                            src, dst, gcur, pairbuf);
  k_partB<<<NBK, 512, 0, stream>>>(pairbuf, gcur, esrc, rowp2);

  int nbG = (NN + 63) / 64;   // 1563
  int nbS = (NN * 8) / 256;   // 3125 blocks per slab pass
  // layer 1: two slab passes, then GEMM (writes hb in slab layout)
  k_agg<<<nbS, 256, 0, stream>>>((const uint2*)xb, rowp2, esrc, (uint2*)aggb);
  k_agg<<<nbS, 256, 0, stream>>>((const uint2*)xb + (size_t)NN * 8, rowp2, esrc,
                                 (uint2*)aggb + (size_t)NN * 8);
  k_gemm<64><<<nbG, 256, 0, stream>>>(aggb, xb, WT1, b1, nullptr, hb, 1);
  // layer 2
  k_agg<<<nbS, 256, 0, stream>>>((const uint2*)hb, rowp2, esrc, (uint2*)aggb);
  k_agg<<<nbS, 256, 0, stream>>>((const uint2*)hb + (size_t)NN * 8, rowp2, esrc,
                                 (uint2*)aggb + (size_t)NN * 8);
  k_gemm<32><<<nbG, 256, 0, stream>>>(aggb, hb, WT2, b2, out, nullptr, 0);
}

// Round 17
// 130.900 us; speedup vs baseline: 1.2144x; 1.2144x over previous
//
#include <hip/hip_runtime.h>

#define NN 100000
#define NE 1600000
#define NBK 392        // ceil(100000/256) buckets of 256 nodes
#define CAPB 6144      // per-bucket edge capacity (mean 4082)
#define CVTB 6250      // (NN*64)/1024 blocks for x->bf16

typedef __attribute__((ext_vector_type(8))) short bf16x8;
typedef __attribute__((ext_vector_type(4))) float f32x4;

__device__ __forceinline__ unsigned short f2b(float f) {
  unsigned b = __float_as_uint(f);
  unsigned r = b + 0x7FFF + ((b >> 16) & 1);  // RNE
  return (unsigned short)(r >> 16);
}

__global__ void k_zero(int* __restrict__ g) {
  if (threadIdx.x < NBK) g[threadIdx.x] = 0;
}

// Fused prologue: [0,CVTB) x->bf16 | CVTB: WT1 | CVTB+1: WT2 | rest: partA.
// partA: hist -> block scan -> global reserve -> LDS bucket-grouped scatter ->
// coalesced writeout.
__global__ void k_pre(const float* __restrict__ x, unsigned short* __restrict__ xb,
                      const float* __restrict__ W1l, const float* __restrict__ W1r,
                      unsigned short* __restrict__ WT1,
                      const float* __restrict__ W2l, const float* __restrict__ W2r,
                      unsigned short* __restrict__ WT2,
                      const int* __restrict__ src, const int* __restrict__ dst,
                      int* __restrict__ gcur, unsigned* __restrict__ pairbuf) {
  __shared__ int hist[NBK];       // after scan phase holds block-local excl. prefix
  __shared__ int sc[512];
  __shared__ int base[NBK], lofs[NBK];
  __shared__ unsigned epk[4096];
  __shared__ unsigned short ebk[4096];
  int t = threadIdx.x;
  int b = blockIdx.x;
  if (b < CVTB) {
    int i = (b * 256 + t) * 4;
    float4 v = *(const float4*)(x + i);
    ushort4 o;
    o.x = f2b(v.x); o.y = f2b(v.y); o.z = f2b(v.z); o.w = f2b(v.w);
    *(ushort4*)(xb + i) = o;
    return;
  }
  if (b == CVTB) {
    for (int i = t; i < 64 * 128; i += 256) {
      int f = i >> 7, k = i & 127;
      WT1[i] = f2b((k < 64) ? W1l[k * 64 + f] : W1r[(k - 64) * 64 + f]);
    }
    return;
  }
  if (b == CVTB + 1) {
    for (int i = t; i < 32 * 128; i += 256) {
      int f = i >> 7, k = i & 127;
      WT2[i] = f2b((k < 64) ? W2l[k * 32 + f] : W2r[(k - 64) * 32 + f]);
    }
    return;
  }
  // ---- partA ----
  int pb = b - (CVTB + 2);
  for (int i = t; i < NBK; i += 256) { hist[i] = 0; lofs[i] = 0; }
  __syncthreads();
  unsigned pk[16]; int bk[16];
  int e0 = pb * 4096 + t;
#pragma unroll
  for (int j = 0; j < 16; ++j) {
    int e = e0 + j * 256;
    if (e < NE) {
      int d = dst[e], s = src[e];
      bk[j] = d >> 8;
      pk[j] = ((unsigned)s << 8) | (unsigned)(d & 255);
      atomicAdd(&hist[bk[j]], 1);
    } else bk[j] = -1;
  }
  __syncthreads();
  sc[t] = (t < NBK) ? hist[t] : 0;
  sc[t + 256] = (t + 256 < NBK) ? hist[t + 256] : 0;
  __syncthreads();
  for (int off = 1; off < 512; off <<= 1) {
    int v0 = (t >= off) ? sc[t - off] : 0;
    int v1 = sc[t + 256 - off];
    __syncthreads();
    sc[t] += v0;
    sc[t + 256] += v1;
    __syncthreads();
  }
  for (int i = t; i < NBK; i += 256) {
    int h = hist[i];
    base[i] = atomicAdd(&gcur[i], h);
    hist[i] = sc[i] - h;
  }
  __syncthreads();
#pragma unroll
  for (int j = 0; j < 16; ++j) {
    if (bk[j] >= 0) {
      int pos = hist[bk[j]] + atomicAdd(&lofs[bk[j]], 1);
      epk[pos] = pk[j];
      ebk[pos] = (unsigned short)bk[j];
    }
  }
  __syncthreads();
  int cb = sc[511];
  for (int i = t; i < cb; i += 256) {
    unsigned p = epk[i];
    int bb = ebk[i];
    int slot = base[bb] + (i - hist[bb]);
    if (slot < CAPB) pairbuf[(size_t)bb * CAPB + slot] = p;
  }
}

// Pass B: one block (512 thr) per bucket. Count -> prefix -> LDS scatter -> writeout.
__global__ void k_partB(const unsigned* __restrict__ pairbuf, const int* __restrict__ gcur,
                        int* __restrict__ esrc, uint2* __restrict__ rowp2) {
  __shared__ int cnt[256], cur[256], ssum[256];
  __shared__ int ebuf[CAPB];
  int b = blockIdx.x, t = threadIdx.x;
  int cb = gcur[b]; if (cb > CAPB) cb = CAPB;
  if (t < 256) cnt[t] = 0;
  __syncthreads();
  const unsigned* pb = pairbuf + (size_t)b * CAPB;
  for (int i = t; i < cb; i += 512) atomicAdd(&cnt[pb[i] & 255], 1);
  __syncthreads();
  int a0 = (t < 256) ? cnt[t] : 0;
  if (t < 256) ssum[t] = a0;
  __syncthreads();
  for (int off = 1; off < 256; off <<= 1) {
    int tmp = (t < 256 && t >= off) ? ssum[t - off] : 0;
    __syncthreads();
    if (t < 256) ssum[t] += tmp;
    __syncthreads();
  }
  if (t < 256) {
    int ex = ssum[t] - a0;
    cur[t] = ex;
    int n = b * 256 + t;
    if (n < NN) rowp2[n] = make_uint2((unsigned)(b * CAPB + ex),
                                      (unsigned)(b * CAPB + ex + a0));
  }
  __syncthreads();
  for (int i = t; i < cb; i += 512) {
    unsigned p = pb[i];
    int pos = atomicAdd(&cur[p & 255], 1);
    ebuf[pos] = (int)(p >> 8);
  }
  __syncthreads();
  for (int i = t; i < cb; i += 512) esrc[(size_t)b * CAPB + i] = ebuf[i];
}

// One node per QUARTER-wave, explicit-ILP 16-gather batches.
// Full rounds (16 edges) run UNGUARDED (no selects, no per-gather masks);
// only the tail round keeps guards. shfl sources stay within the caller's
// own quarter (active whenever the caller is) -> ds_bpermute exec rule safe.
__global__ __launch_bounds__(256, 4) void k_agg(
    const uint2* __restrict__ fb64, const uint2* __restrict__ rowp2,
    const int* __restrict__ esrc, uint2* __restrict__ aggb64) {
  int tid = blockIdx.x * 256 + threadIdx.x;
  int node = tid >> 4;
  int c16 = tid & 15;
  int qbase = threadIdx.x & 48;
  unsigned long long rp =
      __builtin_nontemporal_load((const unsigned long long*)&rowp2[node]);
  int beg = (int)(unsigned)rp;
  int deg = (int)(unsigned)(rp >> 32) - beg;
  float a0 = 0.f, a1 = 0.f, a2 = 0.f, a3 = 0.f;

  int nfull = deg & ~15;
  for (int r0 = 0; r0 < nfull; r0 += 16) {
    int idxv = __builtin_nontemporal_load(&esrc[beg + r0 + c16]);
    int sv[16];
#pragma unroll
    for (int j = 0; j < 16; ++j) sv[j] = __shfl(idxv, qbase + j);
    uint2 v[16];
#pragma unroll
    for (int j = 0; j < 16; ++j) v[j] = fb64[(size_t)sv[j] * 16 + c16];
    __builtin_amdgcn_sched_barrier(0);  // keep gather batch above the accum chain
#pragma unroll
    for (int j = 0; j < 16; ++j) {
      a0 += __uint_as_float(v[j].x << 16);
      a1 += __uint_as_float(v[j].x & 0xFFFF0000u);
      a2 += __uint_as_float(v[j].y << 16);
      a3 += __uint_as_float(v[j].y & 0xFFFF0000u);
    }
  }
  int rem = deg - nfull;
  if (rem) {
    int idxv = __builtin_nontemporal_load(&esrc[beg + nfull + (c16 < rem ? c16 : 0)]);
    int sv[16];
#pragma unroll
    for (int j = 0; j < 16; ++j) sv[j] = __shfl(idxv, qbase + j);
    uint2 v[16];
#pragma unroll
    for (int j = 0; j < 16; ++j)
      if (j < rem) v[j] = fb64[(size_t)sv[j] * 16 + c16];
    __builtin_amdgcn_sched_barrier(0);
#pragma unroll
    for (int j = 0; j < 16; ++j)
      if (j < rem) {
        a0 += __uint_as_float(v[j].x << 16);
        a1 += __uint_as_float(v[j].x & 0xFFFF0000u);
        a2 += __uint_as_float(v[j].y << 16);
        a3 += __uint_as_float(v[j].y & 0xFFFF0000u);
      }
  }
  float inv = (deg > 0) ? (1.0f / (float)deg) : 0.f;
  uint2 o;
  o.x = (unsigned)f2b(a0 * inv) | ((unsigned)f2b(a1 * inv) << 16);
  o.y = (unsigned)f2b(a2 * inv) | ((unsigned)f2b(a3 * inv) << 16);
  aggb64[(size_t)node * 16 + c16] = o;
}

// MFMA GEMM: out[n][f] = sum_k [aggb|featb][n][k] * WT[f][k] + bias[f], K=128 bf16.
template <int NF>
__global__ __launch_bounds__(256) void k_gemm(
    const unsigned short* __restrict__ aggb, const unsigned short* __restrict__ featb,
    const unsigned short* __restrict__ WT, const float* __restrict__ bias,
    float* __restrict__ out, unsigned short* __restrict__ ob, int relu) {
  __shared__ unsigned short As[64 * 128];
  __shared__ unsigned short Ws[NF * 128];
  int tid = threadIdx.x;
  int n0 = blockIdx.x * 64;
  int lane = tid & 63, wr = tid >> 6;

  for (int cch = tid; cch < 64 * 16; cch += 256) {
    int r = cch >> 4, s = cch & 15;
    int n = n0 + r;
    bf16x8 v = {0, 0, 0, 0, 0, 0, 0, 0};
    if (n < NN) {
      const unsigned short* p = (s < 8) ? (aggb + (size_t)n * 64 + s * 8)
                                        : (featb + (size_t)n * 64 + (s - 8) * 8);
      v = *(const bf16x8*)p;
    }
    *(bf16x8*)(&As[r * 128 + ((s ^ (r & 15)) << 3)]) = v;
  }
  for (int cch = tid; cch < NF * 16; cch += 256) {
    int f = cch >> 4, s = cch & 15;
    bf16x8 v = *(const bf16x8*)(WT + f * 128 + s * 8);
    *(bf16x8*)(&Ws[f * 128 + ((s ^ (f & 15)) << 3)]) = v;
  }
  __syncthreads();

  int l15 = lane & 15, lg = lane >> 4;
  int arow = wr * 16 + l15;
  f32x4 acc[NF / 16];
#pragma unroll
  for (int ct = 0; ct < NF / 16; ++ct) acc[ct] = (f32x4){0.f, 0.f, 0.f, 0.f};

#pragma unroll
  for (int k0 = 0; k0 < 4; ++k0) {
    int sa = k0 * 4 + lg;
    bf16x8 a = *(const bf16x8*)(&As[arow * 128 + ((sa ^ (arow & 15)) << 3)]);
#pragma unroll
    for (int ct = 0; ct < NF / 16; ++ct) {
      int bcol = ct * 16 + l15;
      bf16x8 b = *(const bf16x8*)(&Ws[bcol * 128 + ((sa ^ (bcol & 15)) << 3)]);
      acc[ct] = __builtin_amdgcn_mfma_f32_16x16x32_bf16(a, b, acc[ct], 0, 0, 0);
    }
  }

#pragma unroll
  for (int ct = 0; ct < NF / 16; ++ct) {
    int f = ct * 16 + l15;
    float bv = bias[f];
#pragma unroll
    for (int r = 0; r < 4; ++r) {
      int n = n0 + wr * 16 + lg * 4 + r;
      if (n >= NN) continue;
      float v = acc[ct][r] + bv;
      if (relu) v = fmaxf(v, 0.f);
      if (out) out[(size_t)n * NF + f] = v;
      if (ob) ob[(size_t)n * NF + f] = f2b(v);
    }
  }
}

extern "C" void kernel_launch(void* const* d_in, const int* in_sizes, int n_in,
                              void* d_out, int out_size, void* d_ws, size_t ws_size,
                              hipStream_t stream) {
  const float* x   = (const float*)d_in[0];
  const int*   ei  = (const int*)d_in[1];
  const float* W1l = (const float*)d_in[2];
  const float* W1r = (const float*)d_in[3];
  const float* b1  = (const float*)d_in[4];
  const float* W2l = (const float*)d_in[5];
  const float* W2r = (const float*)d_in[6];
  const float* b2  = (const float*)d_in[7];
  const int* src = ei;
  const int* dst = ei + NE;
  float* out = (float*)d_out;

  char* ws = (char*)d_ws;
  size_t off = 0;
  auto take = [&](size_t bytes) -> char* {
    char* p = ws + off;
    off = (off + bytes + 255) & ~(size_t)255;
    return p;
  };
  int*      gcur    = (int*)take((size_t)NBK * 4);
  unsigned* pairbuf = (unsigned*)take((size_t)NBK * CAPB * 4);
  int*      esrc    = (int*)take((size_t)NBK * CAPB * 4);
  uint2*    rowp2   = (uint2*)take((size_t)NN * 8);
  unsigned short* aggb = (unsigned short*)take((size_t)NN * 64 * 2);
  unsigned short* xb   = (unsigned short*)take((size_t)NN * 64 * 2);
  unsigned short* hb   = (unsigned short*)take((size_t)NN * 64 * 2);
  unsigned short* WT1  = (unsigned short*)take((size_t)64 * 128 * 2);
  unsigned short* WT2  = (unsigned short*)take((size_t)32 * 128 * 2);

  int nbA = (NE + 4095) / 4096;  // 391
  k_zero<<<1, 512, 0, stream>>>(gcur);
  k_pre<<<CVTB + 2 + nbA, 256, 0, stream>>>(x, xb, W1l, W1r, WT1, W2l, W2r, WT2,
                                            src, dst, gcur, pairbuf);
  k_partB<<<NBK, 512, 0, stream>>>(pairbuf, gcur, esrc, rowp2);

  int nbG = (NN + 63) / 64;  // 1563
  // layer 1: 16 nodes per 256-thr block
  k_agg<<<NN / 16, 256, 0, stream>>>((const uint2*)xb, rowp2, esrc, (uint2*)aggb);
  k_gemm<64><<<nbG, 256, 0, stream>>>(aggb, xb, WT1, b1, nullptr, hb, 1);
  // layer 2
  k_agg<<<NN / 16, 256, 0, stream>>>((const uint2*)hb, rowp2, esrc, (uint2*)aggb);
  k_gemm<32><<<nbG, 256, 0, stream>>>(aggb, hb, WT2, b2, out, nullptr, 0);
}